// Round 4
// baseline (545.766 us; speedup 1.0000x reference)
//
#include <hip/hip_runtime.h>
#include <stdint.h>

// HierarchicalGRU on MI355X. B=16384, IN=4096, H=128, NOPT=64.
// Round 4: inputs/outputs are FP32 (reference dtype; rounds 0-3 NaN'd because
// fp32 bits were read as bf16 -> inf/NaN garbage). MFMA path with on-the-fly
// fp32->bf16 conversion; weights pre-transposed+converted to bf16 [N,K] in ws.

typedef __attribute__((ext_vector_type(8))) short bf16x8;
typedef __attribute__((ext_vector_type(4))) float f32x4;
typedef __attribute__((ext_vector_type(4))) float f4;
typedef __attribute__((ext_vector_type(4))) unsigned short u16x4;

#define INDIM 4096
#define H 128
#define NOPT 64

// workspace layout (uint16 element offsets), bf16 contents
#define WS_WAT    0u        // [128, 4096]
#define WS_WIH0T  524288u   // [384, 128]
#define WS_WHH0T  573440u   // [384, 128]
#define WS_WIH1T  622592u   // [384, 256]
#define WS_WHH1T  720896u   // [384, 128]
#define WS_WV0T   770048u   // [64, 128]
#define WS_WV1T   778240u   // [64, 128]
#define WS_WT0T   786432u   // [64, 128]
#define WS_ATTN   794624u   // [16384, 128] bf16

// output layout (fp32 element offsets): v0[B,64], term_p[B,1], v1[B,64], h0n[B,128], h1n[B,128]
#define OUT_V0    0u
#define OUT_TERMP 1048576u
#define OUT_V1    1064960u
#define OUT_H0N   2113536u
#define OUT_H1N   4210688u

static __device__ __forceinline__ float bf2f(uint16_t u) {
  union { uint32_t i; float f; } x; x.i = ((uint32_t)u) << 16; return x.f;
}
static __device__ __forceinline__ uint16_t f2bf(float f) {
  union { float f; uint32_t i; } x; x.f = f;
  uint32_t r = x.i + 0x7fffu + ((x.i >> 16) & 1u);
  return (uint16_t)(r >> 16);
}
static __device__ __forceinline__ float sigm(float x) { return 1.0f / (1.0f + __expf(-x)); }
static __device__ __forceinline__ float fast_tanh(float x) {
  float e = __expf(2.0f * x);          // e=inf -> 1, e=0 -> -1: saturates correctly
  return 1.0f - 2.0f / (e + 1.0f);
}
static __device__ __forceinline__ f32x4 mfma16(bf16x8 a, bf16x8 b, f32x4 c) {
  return __builtin_amdgcn_mfma_f32_16x16x32_bf16(a, b, c, 0, 0, 0);
}
static __device__ __forceinline__ u16x4 pack4(f4 v) {
  u16x4 p;
  p[0] = f2bf(v[0]); p[1] = f2bf(v[1]); p[2] = f2bf(v[2]); p[3] = f2bf(v[3]);
  return p;
}

// ---------------- K0: weight transpose+convert  W[K,N] fp32 -> WT[N,K] bf16 ----------------
__global__ void k_transpose(const float* __restrict__ Wa,
                            const float* __restrict__ Wih0,
                            const float* __restrict__ Whh0,
                            const float* __restrict__ Wih1,
                            const float* __restrict__ Whh1,
                            const float* __restrict__ Wv0,
                            const float* __restrict__ Wv1,
                            const float* __restrict__ Wt0,
                            uint16_t* __restrict__ ws) {
  int blk = blockIdx.x;
  const float* in; uint16_t* out; int ksh; int N; int base;
  if (blk < 2048)      { in = Wa;   out = ws + WS_WAT;   ksh = 12; N = 128; base = 0; }
  else if (blk < 2240) { in = Wih0; out = ws + WS_WIH0T; ksh = 7;  N = 384; base = 2048; }
  else if (blk < 2432) { in = Whh0; out = ws + WS_WHH0T; ksh = 7;  N = 384; base = 2240; }
  else if (blk < 2816) { in = Wih1; out = ws + WS_WIH1T; ksh = 8;  N = 384; base = 2432; }
  else if (blk < 3008) { in = Whh1; out = ws + WS_WHH1T; ksh = 7;  N = 384; base = 2816; }
  else if (blk < 3040) { in = Wv0;  out = ws + WS_WV0T;  ksh = 7;  N = 64;  base = 3008; }
  else if (blk < 3072) { in = Wv1;  out = ws + WS_WV1T;  ksh = 7;  N = 64;  base = 3040; }
  else                 { in = Wt0;  out = ws + WS_WT0T;  ksh = 7;  N = 64;  base = 3072; }
  int e = (blk - base) * 256 + (int)threadIdx.x;
  int n = e >> ksh;
  int k = e & ((1 << ksh) - 1);
  out[e] = f2bf(in[(size_t)k * N + n]);
}

// ---------------- K1: attn = tanh(obs @ Wa + ba) -> ws (bf16) ----------------
// 32 rows x 128 cols per block, 2 waves, K-tile 64. XOR-swizzled LDS slots.
__launch_bounds__(128)
__global__ void k_attn(const float* __restrict__ obs,
                       uint16_t* __restrict__ ws,
                       const float* __restrict__ ba) {
  __shared__ uint16_t sA[32 * 64];   // row r, phys 8-elt slot c holds k-block c^(r&7)
  __shared__ uint16_t sB[128 * 64];
  const uint16_t* WaT = ws + WS_WAT;
  uint16_t* attn = ws + WS_ATTN;
  const int t = threadIdx.x, w = t >> 6, lane = t & 63;
  const int l15 = lane & 15, quad = lane >> 4;
  const int row0 = blockIdx.x * 32;
  f32x4 acc[8] = {};
  const int rA = 16 * w + l15;
  for (int kt = 0; kt < 64; ++kt) {
    const int k0 = kt * 64;
    f4 va[4]; bf16x8 vb[8];
#pragma unroll
    for (int i = 0; i < 4; ++i) {  // A: 32 rows x 16 4-elt blocks (fp32 source)
      int p = i * 128 + t, r = p >> 4, kb4 = p & 15;
      va[i] = *(const f4*)(obs + (size_t)(row0 + r) * INDIM + k0 + kb4 * 4);
    }
#pragma unroll
    for (int i = 0; i < 8; ++i) {  // B: 128 rows x 8 8-elt blocks (bf16 ws)
      int p = i * 128 + t, n = p >> 3, kb = p & 7;
      vb[i] = *(const bf16x8*)(WaT + (size_t)n * INDIM + k0 + kb * 8);
    }
    __syncthreads();  // previous iteration's fragment reads complete
#pragma unroll
    for (int i = 0; i < 4; ++i) {
      int p = i * 128 + t, r = p >> 4, kb4 = p & 15;
      int c8 = (kb4 >> 1) ^ (r & 7);
      *(u16x4*)&sA[(r * 8 + c8) * 8 + (kb4 & 1) * 4] = pack4(va[i]);
    }
#pragma unroll
    for (int i = 0; i < 8; ++i) {
      int p = i * 128 + t, n = p >> 3, kb = p & 7;
      *(bf16x8*)&sB[(n * 8 + (kb ^ (n & 7))) * 8] = vb[i];
    }
    __syncthreads();  // staging visible
#pragma unroll
    for (int ks = 0; ks < 2; ++ks) {
      const int kb = ks * 4 + quad;
      bf16x8 a = *(const bf16x8*)&sA[(rA * 8 + (kb ^ (rA & 7))) * 8];
#pragma unroll
      for (int nb = 0; nb < 8; ++nb) {
        int nB = nb * 16 + l15;
        bf16x8 b = *(const bf16x8*)&sB[(nB * 8 + (kb ^ (nB & 7))) * 8];
        acc[nb] = mfma16(a, b, acc[nb]);
      }
    }
  }
#pragma unroll
  for (int nb = 0; nb < 8; ++nb) {
    int col = nb * 16 + l15;
    float bav = ba[col];
#pragma unroll
    for (int i = 0; i < 4; ++i) {
      int grow = row0 + 16 * w + quad * 4 + i;  // C/D: col=lane&15, row=quad*4+reg
      attn[(size_t)grow * H + col] = f2bf(fast_tanh(acc[nb][i] + bav));
    }
  }
}

// ---------------- K2: GRU layer 0 + v0/term heads ----------------
__launch_bounds__(128)
__global__ void k_gru0(const uint16_t* __restrict__ ws,
                       const float* __restrict__ h0,
                       const float* __restrict__ bih0,
                       const float* __restrict__ bhh0,
                       const float* __restrict__ bv0,
                       const float* __restrict__ bt0,
                       const int* __restrict__ chosen,
                       float* __restrict__ out) {
  __shared__ uint16_t sX[32 * 128];  // row r, phys 8-elt slot c holds k-block c^(r&15)
  __shared__ uint16_t sH[32 * 128];
  __shared__ uint16_t sC[32 * 128];  // hc0 tile, same swizzle
  const uint16_t* attn = ws + WS_ATTN;
  const uint16_t* WihT = ws + WS_WIH0T;  // [384,128]
  const uint16_t* WhhT = ws + WS_WHH0T;  // [384,128]
  const uint16_t* WvT  = ws + WS_WV0T;   // [64,128]
  const uint16_t* WtT  = ws + WS_WT0T;   // [64,128]
  const int t = threadIdx.x, w = t >> 6, lane = t & 63;
  const int l15 = lane & 15, quad = lane >> 4;
  const int row0 = blockIdx.x * 32;
  {
    bf16x8 vx[4]; f4 vh[8];
#pragma unroll
    for (int i = 0; i < 4; ++i) {  // attn: 32 rows x 16 8-elt blocks (bf16)
      int p = i * 128 + t, r = p >> 4, kb = p & 15;
      vx[i] = *(const bf16x8*)(attn + (size_t)(row0 + r) * H + kb * 8);
    }
#pragma unroll
    for (int i = 0; i < 8; ++i) {  // h0: 32 rows x 32 4-elt blocks (fp32)
      int p = i * 128 + t, r = p >> 5, kb4 = p & 31;
      vh[i] = *(const f4*)(h0 + (size_t)(row0 + r) * H + kb4 * 4);
    }
#pragma unroll
    for (int i = 0; i < 4; ++i) {
      int p = i * 128 + t, r = p >> 4, kb = p & 15;
      *(bf16x8*)&sX[(r * 16 + (kb ^ (r & 15))) * 8] = vx[i];
    }
#pragma unroll
    for (int i = 0; i < 8; ++i) {
      int p = i * 128 + t, r = p >> 5, kb4 = p & 31;
      int c8 = (kb4 >> 1) ^ (r & 15);
      *(u16x4*)&sH[(r * 16 + c8) * 8 + (kb4 & 1) * 4] = pack4(vh[i]);
    }
  }
  __syncthreads();
  const int rA = 16 * w + l15;
  bf16x8 ax[4], ah[4];
#pragma unroll
  for (int ks = 0; ks < 4; ++ks) {
    int kb = ks * 4 + quad;
    int sl = rA * 16 + (kb ^ (rA & 15));
    ax[ks] = *(const bf16x8*)&sX[sl * 8];
    ah[ks] = *(const bf16x8*)&sH[sl * 8];
  }
#pragma unroll
  for (int nb = 0; nb < 8; ++nb) {
    f32x4 air = {}, ahr = {}, aiz = {}, ahz = {}, ain = {}, ahn = {};
    int nrow = nb * 16 + l15;
#pragma unroll
    for (int ks = 0; ks < 4; ++ks) {
      int k = ks * 32 + quad * 8;
      bf16x8 b;
      b = *(const bf16x8*)(WihT + (size_t)(nrow      ) * H + k); air = mfma16(ax[ks], b, air);
      b = *(const bf16x8*)(WihT + (size_t)(nrow + 128) * H + k); aiz = mfma16(ax[ks], b, aiz);
      b = *(const bf16x8*)(WihT + (size_t)(nrow + 256) * H + k); ain = mfma16(ax[ks], b, ain);
      b = *(const bf16x8*)(WhhT + (size_t)(nrow      ) * H + k); ahr = mfma16(ah[ks], b, ahr);
      b = *(const bf16x8*)(WhhT + (size_t)(nrow + 128) * H + k); ahz = mfma16(ah[ks], b, ahz);
      b = *(const bf16x8*)(WhhT + (size_t)(nrow + 256) * H + k); ahn = mfma16(ah[ks], b, ahn);
    }
    int col = nb * 16 + l15;
    float b_ir = bih0[col],       b_hr = bhh0[col];
    float b_iz = bih0[col + 128], b_hz = bhh0[col + 128];
    float b_in = bih0[col + 256], b_hn = bhh0[col + 256];
    int slc = col >> 3;
#pragma unroll
    for (int i = 0; i < 4; ++i) {
      int r = 16 * w + quad * 4 + i;
      int grow = row0 + r;
      float rr = sigm(air[i] + ahr[i] + b_ir + b_hr);
      float zz = sigm(aiz[i] + ahz[i] + b_iz + b_hz);
      float nn = fast_tanh(ain[i] + b_in + rr * (ahn[i] + b_hn));
      float hv = bf2f(sH[(r * 16 + (slc ^ (r & 15))) * 8 + (col & 7)]);
      float hnew = (1.0f - zz) * nn + zz * hv;
      out[OUT_H0N + (size_t)grow * H + col] = hnew;
      sC[(r * 16 + (slc ^ (r & 15))) * 8 + (col & 7)] = f2bf(0.5f * hnew + 0.25f);
    }
  }
  __syncthreads();  // sC fully visible before head fragment reads
  bf16x8 ac[4];
#pragma unroll
  for (int ks = 0; ks < 4; ++ks) {
    int kb = ks * 4 + quad;
    ac[ks] = *(const bf16x8*)&sC[(rA * 16 + (kb ^ (rA & 15))) * 8];
  }
#pragma unroll
  for (int vb = 0; vb < 4; ++vb) {
    f32x4 av = {}, at = {};
    int nrow = vb * 16 + l15;
#pragma unroll
    for (int ks = 0; ks < 4; ++ks) {
      int k = ks * 32 + quad * 8;
      bf16x8 b;
      b = *(const bf16x8*)(WvT + (size_t)nrow * H + k); av = mfma16(ac[ks], b, av);
      b = *(const bf16x8*)(WtT + (size_t)nrow * H + k); at = mfma16(ac[ks], b, at);
    }
    int col = vb * 16 + l15;
    float bvv = bv0[col], btv = bt0[col];
#pragma unroll
    for (int i = 0; i < 4; ++i) {
      int grow = row0 + 16 * w + quad * 4 + i;
      out[OUT_V0 + (size_t)grow * NOPT + col] = av[i] + bvv;
      if (chosen[grow] == col)
        out[OUT_TERMP + grow] = sigm(at[i] + btv);
    }
  }
}

// ---------------- K3: GRU layer 1 (x1 = [attn|h1]) + v1 head ----------------
__launch_bounds__(128)
__global__ void k_gru1(const uint16_t* __restrict__ ws,
                       const float* __restrict__ h1,
                       const float* __restrict__ bih1,
                       const float* __restrict__ bhh1,
                       const float* __restrict__ bv1,
                       float* __restrict__ out) {
  __shared__ uint16_t sX[32 * 128];
  __shared__ uint16_t sH[32 * 128];
  __shared__ uint16_t sC[32 * 128];
  const uint16_t* attn  = ws + WS_ATTN;
  const uint16_t* WihT  = ws + WS_WIH1T;  // [384,256]
  const uint16_t* WhhT  = ws + WS_WHH1T;  // [384,128]
  const uint16_t* WvT   = ws + WS_WV1T;   // [64,128]
  const int t = threadIdx.x, w = t >> 6, lane = t & 63;
  const int l15 = lane & 15, quad = lane >> 4;
  const int row0 = blockIdx.x * 32;
  {
    bf16x8 vx[4]; f4 vh[8];
#pragma unroll
    for (int i = 0; i < 4; ++i) {
      int p = i * 128 + t, r = p >> 4, kb = p & 15;
      vx[i] = *(const bf16x8*)(attn + (size_t)(row0 + r) * H + kb * 8);
    }
#pragma unroll
    for (int i = 0; i < 8; ++i) {
      int p = i * 128 + t, r = p >> 5, kb4 = p & 31;
      vh[i] = *(const f4*)(h1 + (size_t)(row0 + r) * H + kb4 * 4);
    }
#pragma unroll
    for (int i = 0; i < 4; ++i) {
      int p = i * 128 + t, r = p >> 4, kb = p & 15;
      *(bf16x8*)&sX[(r * 16 + (kb ^ (r & 15))) * 8] = vx[i];
    }
#pragma unroll
    for (int i = 0; i < 8; ++i) {
      int p = i * 128 + t, r = p >> 5, kb4 = p & 31;
      int c8 = (kb4 >> 1) ^ (r & 15);
      *(u16x4*)&sH[(r * 16 + c8) * 8 + (kb4 & 1) * 4] = pack4(vh[i]);
    }
  }
  __syncthreads();
  const int rA = 16 * w + l15;
  bf16x8 ax[4], ah[4];
#pragma unroll
  for (int ks = 0; ks < 4; ++ks) {
    int kb = ks * 4 + quad;
    int sl = rA * 16 + (kb ^ (rA & 15));
    ax[ks] = *(const bf16x8*)&sX[sl * 8];
    ah[ks] = *(const bf16x8*)&sH[sl * 8];
  }
#pragma unroll
  for (int nb = 0; nb < 8; ++nb) {
    f32x4 air = {}, ahr = {}, aiz = {}, ahz = {}, ain = {}, ahn = {};
    int nrow = nb * 16 + l15;
#pragma unroll
    for (int ks = 0; ks < 8; ++ks) {  // gi1 over K=256: x1 = [attn|h1]
      int k = ks * 32 + quad * 8;
      bf16x8 a = (ks < 4) ? ax[ks] : ah[ks - 4];
      bf16x8 b;
      b = *(const bf16x8*)(WihT + (size_t)(nrow      ) * 256 + k); air = mfma16(a, b, air);
      b = *(const bf16x8*)(WihT + (size_t)(nrow + 128) * 256 + k); aiz = mfma16(a, b, aiz);
      b = *(const bf16x8*)(WihT + (size_t)(nrow + 256) * 256 + k); ain = mfma16(a, b, ain);
    }
#pragma unroll
    for (int ks = 0; ks < 4; ++ks) {  // gh1 over K=128
      int k = ks * 32 + quad * 8;
      bf16x8 b;
      b = *(const bf16x8*)(WhhT + (size_t)(nrow      ) * H + k); ahr = mfma16(ah[ks], b, ahr);
      b = *(const bf16x8*)(WhhT + (size_t)(nrow + 128) * H + k); ahz = mfma16(ah[ks], b, ahz);
      b = *(const bf16x8*)(WhhT + (size_t)(nrow + 256) * H + k); ahn = mfma16(ah[ks], b, ahn);
    }
    int col = nb * 16 + l15;
    float b_ir = bih1[col],       b_hr = bhh1[col];
    float b_iz = bih1[col + 128], b_hz = bhh1[col + 128];
    float b_in = bih1[col + 256], b_hn = bhh1[col + 256];
    int slc = col >> 3;
#pragma unroll
    for (int i = 0; i < 4; ++i) {
      int r = 16 * w + quad * 4 + i;
      int grow = row0 + r;
      float rr = sigm(air[i] + ahr[i] + b_ir + b_hr);
      float zz = sigm(aiz[i] + ahz[i] + b_iz + b_hz);
      float nn = fast_tanh(ain[i] + b_in + rr * (ahn[i] + b_hn));
      float hv = bf2f(sH[(r * 16 + (slc ^ (r & 15))) * 8 + (col & 7)]);
      float hnew = (1.0f - zz) * nn + zz * hv;
      out[OUT_H1N + (size_t)grow * H + col] = hnew;
      sC[(r * 16 + (slc ^ (r & 15))) * 8 + (col & 7)] = f2bf(0.5f * hnew + 0.25f);
    }
  }
  __syncthreads();
  bf16x8 ac[4];
#pragma unroll
  for (int ks = 0; ks < 4; ++ks) {
    int kb = ks * 4 + quad;
    ac[ks] = *(const bf16x8*)&sC[(rA * 16 + (kb ^ (rA & 15))) * 8];
  }
#pragma unroll
  for (int vb = 0; vb < 4; ++vb) {
    f32x4 av = {};
    int nrow = vb * 16 + l15;
#pragma unroll
    for (int ks = 0; ks < 4; ++ks) {
      int k = ks * 32 + quad * 8;
      bf16x8 b = *(const bf16x8*)(WvT + (size_t)nrow * H + k);
      av = mfma16(ac[ks], b, av);
    }
    int col = vb * 16 + l15;
    float bvv = bv1[col];
#pragma unroll
    for (int i = 0; i < 4; ++i) {
      int grow = row0 + 16 * w + quad * 4 + i;
      out[OUT_V1 + (size_t)grow * NOPT + col] = av[i] + bvv;
    }
  }
}

extern "C" void kernel_launch(void* const* d_in, const int* in_sizes, int n_in,
                              void* d_out, int out_size, void* d_ws, size_t ws_size,
                              hipStream_t stream) {
  (void)in_sizes; (void)n_in; (void)out_size; (void)ws_size;
  const float* obs    = (const float*)d_in[0];
  const int*   chosen = (const int*)d_in[1];
  const float* h0     = (const float*)d_in[2];
  const float* h1     = (const float*)d_in[3];
  const float* Wa     = (const float*)d_in[4];
  const float* ba     = (const float*)d_in[5];
  const float* Wih0   = (const float*)d_in[6];
  const float* Whh0   = (const float*)d_in[7];
  const float* bih0   = (const float*)d_in[8];
  const float* bhh0   = (const float*)d_in[9];
  const float* Wih1   = (const float*)d_in[10];
  const float* Whh1   = (const float*)d_in[11];
  const float* bih1   = (const float*)d_in[12];
  const float* bhh1   = (const float*)d_in[13];
  const float* Wv0    = (const float*)d_in[14];
  const float* bv0    = (const float*)d_in[15];
  const float* Wv1    = (const float*)d_in[16];
  const float* bv1    = (const float*)d_in[17];
  const float* Wt0    = (const float*)d_in[18];
  const float* bt0    = (const float*)d_in[19];
  uint16_t* ws  = (uint16_t*)d_ws;
  float*    out = (float*)d_out;

  hipLaunchKernelGGL(k_transpose, dim3(3104), dim3(256), 0, stream,
                     Wa, Wih0, Whh0, Wih1, Whh1, Wv0, Wv1, Wt0, ws);
  hipLaunchKernelGGL(k_attn, dim3(512), dim3(128), 0, stream, obs, ws, ba);
  hipLaunchKernelGGL(k_gru0, dim3(512), dim3(128), 0, stream,
                     ws, h0, bih0, bhh0, bv0, bt0, chosen, out);
  hipLaunchKernelGGL(k_gru1, dim3(512), dim3(128), 0, stream,
                     ws, h1, bih1, bhh1, bv1, out);
}